// Round 7
// baseline (40.927 us; speedup 1.0000x reference)
//
#include <hip/hip_runtime.h>
#include <hip/hip_bf16.h>
#include <stdint.h>

#define B_ROWS 8192
#define D_DIM  128
#define TILE   128
#define NSLAB  8

typedef __attribute__((ext_vector_type(8))) __bf16 bf16x8;
typedef __attribute__((ext_vector_type(4))) float  f32x4;

typedef __attribute__((address_space(3))) uint32_t lds_u32;
typedef __attribute__((address_space(1))) const uint32_t glb_u32;

__device__ __forceinline__ float fast_exp2(float x) {
    float r;
    asm("v_exp_f32 %0, %1" : "=v"(r) : "v"(x));
    return r;
}

// ---------------- Kernel 1: l2-normalize rows, cast to bf16 ----------------
__global__ void k_norm(const float* __restrict__ z, __hip_bfloat16* __restrict__ zn) {
    int row  = blockIdx.x * 4 + (threadIdx.x >> 6);
    int lane = threadIdx.x & 63;
    const float2 v = reinterpret_cast<const float2*>(z + (size_t)row * D_DIM)[lane];
    float ss = v.x * v.x + v.y * v.y;
    #pragma unroll
    for (int m = 1; m < 64; m <<= 1) ss += __shfl_xor(ss, m);
    float inv = rsqrtf(fmaxf(ss, 1e-12f));
    __hip_bfloat162 o;
    o.x = __float2bfloat16(v.x * inv);
    o.y = __float2bfloat16(v.y * inv);
    reinterpret_cast<__hip_bfloat162*>(zn + (size_t)row * D_DIM)[lane] = o;
}

// ---------------- Kernel 2: upper-triangle similarity (symmetry-halved) -----
// Pair p = (rt=k, rt=63-k): 65 tiles with ct>=rt. 8 blocks per pair take tile
// indices j, j+8, ... Each off-diagonal tile credits rows (register srow) and
// columns (atomicAdd col_sum). Diagonal tiles computed fully, no col credit.
// A fragments in registers (reloaded once at segment switch); B double-
// buffered in LDS with the R5-proven sync-per-tile prefetch pipeline.
// Swizzle identical to R4-R6 (validated).
__global__ __launch_bounds__(512, 2) void k_sim(const __bf16* __restrict__ zn,
                                                float* __restrict__ row_slab,
                                                float* __restrict__ col_sum,
                                                float* __restrict__ pos) {
    __shared__ __align__(16) char smem[4 * 32768 + TILE * 4 * sizeof(float)];
    char* sA0 = smem;                   // A tile for rt=k
    char* sA1 = smem + 32768;           // A tile for rt=63-k
    char* sB  = smem + 65536;           // 2 x 32 KB B double buffer
    float (*red)[4] = (float (*)[4])(smem + 131072);

    const int tid  = threadIdx.x;
    const int lane = tid & 63;
    const int l15  = lane & 15;
    const int lg   = lane >> 4;         // 0..3
    const int w    = tid >> 6;          // 0..7
    const int wr   = w >> 2;            // 0..1 : rows [wr*64, +64)
    const int wc   = w & 3;             // 0..3 : cols [wc*32, +32)

    const int k    = blockIdx.x >> 3;   // pair 0..31
    const int j    = blockIdx.x & 7;    // sub-block 0..7
    const int rtA  = k;
    const int rtB  = 63 - k;
    const int segStart = 64 - k;        // idx >= segStart -> rt = rtB
    const int M    = (72 - j) >> 3;     // 9 tiles for j==0, else 8
    const int swM  = (segStart - j + 7) >> 3;  // first m in segment B (may be >= M)

    auto stage = [&](int gRowBase, char* dst) {
        #pragma unroll
        for (int q = 0; q < 4; ++q) {
            int slot = q * 512 + tid;
            int row  = slot >> 4;
            int u    = slot & 15;
            const __bf16* g = zn + (size_t)(gRowBase + row) * D_DIM + ((u ^ (row & 7)) << 3);
            __builtin_amdgcn_global_load_lds((glb_u32*)g, (lds_u32*)(dst + slot * 16), 16, 0, 0);
        }
    };

    const float C1 = 2.0f * 1.4426950408889634f;   // sim = 2*dot (tau = 0.5)
    const float C0 = -2.0f * 1.4426950408889634f;  // exp(sim-2) = exp2(dot*C1+C0)

    float srow[4][4];
    #pragma unroll
    for (int t = 0; t < 4; ++t)
        #pragma unroll
        for (int r = 0; r < 4; ++r) srow[t][r] = 0.f;

    bf16x8 afr[4][4];
    auto loadA = [&](const char* src) {
        #pragma unroll
        for (int t = 0; t < 4; ++t)
            #pragma unroll
            for (int ks = 0; ks < 4; ++ks) {
                int row = wr * 64 + t * 16 + l15;
                int kb  = ks * 64 + lg * 16;
                afr[t][ks] = *reinterpret_cast<const bf16x8*>(
                    src + row * 256 + (kb ^ ((row & 7) << 4)));
            }
    };

    auto flushRows = [&](int rt) {
        __syncthreads();
        #pragma unroll
        for (int t = 0; t < 4; ++t)
            #pragma unroll
            for (int r = 0; r < 4; ++r) {
                float v = srow[t][r];
                v += __shfl_xor(v, 1);
                v += __shfl_xor(v, 2);
                v += __shfl_xor(v, 4);
                v += __shfl_xor(v, 8);
                if (l15 == 0) red[wr * 64 + t * 16 + lg * 4 + r][wc] = v;
            }
        __syncthreads();
        if (tid < TILE)
            row_slab[(size_t)j * B_ROWS + rt * TILE + tid] =
                red[tid][0] + red[tid][1] + red[tid][2] + red[tid][3];
    };

    // ---- prologue: both A tiles + first B tile
    stage(rtA * TILE, sA0);
    stage(rtB * TILE, sA1);
    stage((k + j) * TILE, sB);          // tile m=0: idx=j<segStart, ct=k+j
    asm volatile("s_waitcnt vmcnt(0)" ::: "memory");
    __syncthreads();
    loadA(sA0);

    #pragma unroll 1
    for (int m = 0; m < M; ++m) {
        if (m == swM) {                 // uniform: segment switch rtA -> rtB
            flushRows(rtA);
            loadA(sA1);
            #pragma unroll
            for (int t = 0; t < 4; ++t)
                #pragma unroll
                for (int r = 0; r < 4; ++r) srow[t][r] = 0.f;
        }
        if (m + 1 < M) {                // prefetch next B tile
            int nidx = j + 8 * (m + 1);
            int nct  = (nidx < segStart) ? (k + nidx) : (nidx - 1);
            stage(nct * TILE, sB + ((m + 1) & 1) * 32768);
        }
        const int idx = j + 8 * m;
        const int rt  = (idx < segStart) ? rtA : rtB;
        const int ct  = (idx < segStart) ? (k + idx) : (idx - 1);
        const char* bb = sB + (m & 1) * 32768;

        bf16x8 bfr[2][4];
        #pragma unroll
        for (int cs = 0; cs < 2; ++cs)
            #pragma unroll
            for (int ks = 0; ks < 4; ++ks) {
                int row = wc * 32 + cs * 16 + l15;
                int kb  = ks * 64 + lg * 16;
                bfr[cs][ks] = *reinterpret_cast<const bf16x8*>(
                    bb + row * 256 + (kb ^ ((row & 7) << 4)));
            }

        if (rt == ct) {
            // diagonal tile: full compute, self-mask + pos, NO column credit
            #pragma unroll
            for (int t = 0; t < 4; ++t)
                #pragma unroll
                for (int cs = 0; cs < 2; ++cs) {
                    f32x4 acc = {0.f, 0.f, 0.f, 0.f};
                    #pragma unroll
                    for (int ks = 0; ks < 4; ++ks)
                        acc = __builtin_amdgcn_mfma_f32_16x16x32_bf16(afr[t][ks], bfr[cs][ks], acc, 0, 0, 0);
                    if (wr * 64 + t * 16 == wc * 32 + cs * 16) {   // diag frag
                        const int fragBase = rt * TILE + wr * 64 + t * 16;
                        const int col = fragBase + l15;
                        #pragma unroll
                        for (int r = 0; r < 4; ++r) {
                            int row = fragBase + lg * 4 + r;
                            float e = fast_exp2(fmaf(acc[r], C1, C0));
                            if (col == row) e = 0.f;                         // self
                            if (col == (row ^ 1)) pos[row] = acc[r] * 2.0f;  // partner
                            srow[t][r] += e;
                        }
                    } else {
                        #pragma unroll
                        for (int r = 0; r < 4; ++r)
                            srow[t][r] += fast_exp2(fmaf(acc[r], C1, C0));
                    }
                }
        } else {
            // strictly-upper tile: rows direct + columns via transpose credit
            float scol0 = 0.f, scol1 = 0.f;
            #pragma unroll
            for (int t = 0; t < 4; ++t)
                #pragma unroll
                for (int cs = 0; cs < 2; ++cs) {
                    f32x4 acc = {0.f, 0.f, 0.f, 0.f};
                    #pragma unroll
                    for (int ks = 0; ks < 4; ++ks)
                        acc = __builtin_amdgcn_mfma_f32_16x16x32_bf16(afr[t][ks], bfr[cs][ks], acc, 0, 0, 0);
                    float cp = 0.f;
                    #pragma unroll
                    for (int r = 0; r < 4; ++r) {
                        float e = fast_exp2(fmaf(acc[r], C1, C0));
                        srow[t][r] += e;
                        cp += e;
                    }
                    if (cs == 0) scol0 += cp; else scol1 += cp;
                }
            // reduce col partials over the 16 rows per lane-group, then lanes
            scol0 += __shfl_xor(scol0, 16);
            scol0 += __shfl_xor(scol0, 32);
            scol1 += __shfl_xor(scol1, 16);
            scol1 += __shfl_xor(scol1, 32);
            if (lg == 0) {
                atomicAdd(col_sum + ct * TILE + wc * 32 + l15, scol0);
                atomicAdd(col_sum + ct * TILE + wc * 32 + 16 + l15, scol1);
            }
        }
        __syncthreads();   // prefetched B landed; current buffer reusable
    }

    // ---- final flush
    if (swM >= M) {        // block had no rtB tiles
        flushRows(rtA);
        if (tid < TILE) row_slab[(size_t)j * B_ROWS + rtB * TILE + tid] = 0.f;
    } else {
        flushRows(rtB);
    }
}

// ---------------- Kernel 3: per-row loss, per-block partial sums ------------
__global__ void k_loss_partial(const float* __restrict__ slab,
                               const float* __restrict__ col_sum,
                               const float* __restrict__ pos,
                               float* __restrict__ part) {
    int i = blockIdx.x * 256 + threadIdx.x;
    float ssum = col_sum[i];
    #pragma unroll
    for (int s = 0; s < NSLAB; ++s) ssum += slab[(size_t)s * B_ROWS + i];
    float v = 2.0f + logf(ssum) - pos[i];
    #pragma unroll
    for (int m = 1; m < 64; m <<= 1) v += __shfl_xor(v, m);
    __shared__ float ls[4];
    if ((threadIdx.x & 63) == 0) ls[threadIdx.x >> 6] = v;
    __syncthreads();
    if (threadIdx.x == 0) part[blockIdx.x] = ls[0] + ls[1] + ls[2] + ls[3];
}

// ---------------- Kernel 4: final reduce ------------------------------------
__global__ void k_final(const float* __restrict__ part, float* __restrict__ out) {
    float v = (threadIdx.x < (B_ROWS / 256)) ? part[threadIdx.x] : 0.f;
    #pragma unroll
    for (int m = 1; m < 64; m <<= 1) v += __shfl_xor(v, m);
    if (threadIdx.x == 0) out[0] = v * (1.0f / (float)B_ROWS);
}

extern "C" void kernel_launch(void* const* d_in, const int* in_sizes, int n_in,
                              void* d_out, int out_size, void* d_ws, size_t ws_size,
                              hipStream_t stream) {
    const float* z = (const float*)d_in[0];
    float* out = (float*)d_out;

    char* ws = (char*)d_ws;
    __hip_bfloat16* zn = (__hip_bfloat16*)ws;                             // 2 MB
    float* row_slab = (float*)(ws + (size_t)B_ROWS * D_DIM * 2);          // 256 KB
    float* col_sum  = (float*)((char*)row_slab + (size_t)NSLAB * B_ROWS * 4); // 32 KB
    float* pos      = (float*)((char*)col_sum + (size_t)B_ROWS * 4);      // 32 KB
    float* part     = (float*)((char*)pos + (size_t)B_ROWS * 4);          // 128 B

    // 0) col_sum accumulates via atomics -> zero it every launch
    hipMemsetAsync(col_sum, 0, (size_t)B_ROWS * 4, stream);

    // 1) normalize + bf16 cast
    k_norm<<<B_ROWS / 4, 256, 0, stream>>>(z, zn);

    // 2) upper-triangle similarity: 32 pairs x 8 blocks = 256 blocks (1/CU)
    k_sim<<<256, 512, 0, stream>>>((const __bf16*)zn, row_slab, col_sum, pos);

    // 3) per-row loss -> 32 block partials
    k_loss_partial<<<B_ROWS / 256, 256, 0, stream>>>(row_slab, col_sum, pos, part);

    // 4) final scalar
    k_final<<<1, 64, 0, stream>>>(part, out);
}